// Round 11
// baseline (117.066 us; speedup 1.0000x reference)
//
#include <hip/hip_runtime.h>
#include <math.h>

#define NUM_E   1024
#define ZQ_ELEM 8388608         // 32*64*64*64
#define AGRID   256
#define MAXC    7
#define OQCAP   512

typedef short bf16x8 __attribute__((ext_vector_type(8)));
typedef float f32x16 __attribute__((ext_vector_type(16)));

__device__ inline unsigned short rne_bf16(float v) {
    unsigned u = __float_as_uint(v);
    return (unsigned short)((u + 0x7FFFu + ((u >> 16) & 1u)) >> 16);  // RNE, finite-safe
}

// ---------------------------------------------------------------- prep: ee + bf16-hi B fragments
// B-frag layout for mfma_f32_32x32x16_bf16: lane l holds col j = nt*32+(l&31),
// k = kt*16 + (l>>5)*8 + i.  Packet index = (nt*4+kt)*64 + (l>>5)*32 + (j&31).
__global__ __launch_bounds__(256) void vq_prep(const float* __restrict__ cb,
                                               float* __restrict__ ee,
                                               unsigned short* __restrict__ ehi)
{
    int j = blockIdx.x * 256 + threadIdx.x;   // grid 4 -> 1024 codes
    const float* r = cb + (size_t)j * 64;
    float v[64];
#pragma unroll
    for (int k = 0; k < 64; ++k) v[k] = r[k];
    float a = 0.f;
#pragma unroll
    for (int k = 0; k < 64; ++k) a = fmaf(v[k], v[k], a);   // same chain as r1-r10
    ee[j] = a;

    int nt = j >> 5, jc = j & 31;
#pragma unroll
    for (int kt = 0; kt < 4; ++kt)
#pragma unroll
        for (int h = 0; h < 2; ++h) {
            bf16x8 vh;
#pragma unroll
            for (int i = 0; i < 8; ++i)
                vh[i] = (short)rne_bf16(v[kt * 16 + h * 8 + i]);
            *(bf16x8*)(ehi + ((size_t)(nt * 4 + kt) * 64 + h * 32 + jc) * 8) = vh;
        }
}

// exact d for (point pl, code j), z from global, BATCHED loads (16 z + 4 cb-float4
// in flight per chunk); fmaf chain order bit-identical to r1-r10.
__device__ inline unsigned long long key_glob(const float* zb, float zz, float eej,
                                              const float* cb, int pl, int j)
{
    const float4* cr = (const float4*)(cb + ((size_t)j << 6));
    float a = 0.f;
#pragma unroll
    for (int qb = 0; qb < 4; ++qb) {
        float4 c0 = cr[qb * 4 + 0];
        float4 c1 = cr[qb * 4 + 1];
        float4 c2 = cr[qb * 4 + 2];
        float4 c3 = cr[qb * 4 + 3];
        float t[16];
#pragma unroll
        for (int i = 0; i < 16; ++i)
            t[i] = zb[(size_t)(qb * 16 + i) * 4096 + pl];
        a = fmaf(t[0],  c0.x, a); a = fmaf(t[1],  c0.y, a);
        a = fmaf(t[2],  c0.z, a); a = fmaf(t[3],  c0.w, a);
        a = fmaf(t[4],  c1.x, a); a = fmaf(t[5],  c1.y, a);
        a = fmaf(t[6],  c1.z, a); a = fmaf(t[7],  c1.w, a);
        a = fmaf(t[8],  c2.x, a); a = fmaf(t[9],  c2.y, a);
        a = fmaf(t[10], c2.z, a); a = fmaf(t[11], c2.w, a);
        a = fmaf(t[12], c3.x, a); a = fmaf(t[13], c3.y, a);
        a = fmaf(t[14], c3.z, a); a = fmaf(t[15], c3.w, a);
    }
    float t1 = zz + eej;
    float d  = fmaf(-2.f, a, t1);
    return ((unsigned long long)__float_as_uint(d) << 32) | (unsigned long long)j;
}

// ---------------------------------------------------------------- argmin + quant (fused, LDS-resident B)
// Block = 1024 threads = 16 waves = 512 points; grid 256 -> 1 block/CU, 4 waves/SIMD.
// All dependent-load chains batched (MLP); LDS b-regs ping-ponged across nt.
__global__ __launch_bounds__(1024, 4) void vq_argmin(
    const float* __restrict__ z, const float* __restrict__ cb,
    const unsigned short* __restrict__ ehi, const float* __restrict__ ee,
    float* __restrict__ idx_f, int* __restrict__ counts,
    float* __restrict__ zq, double* __restrict__ partials)
{
    __shared__ bf16x8 bB[8192];                 // 128 KB: linear copy of ehi
    __shared__ float  eeL[1024];                // 4 KB
    __shared__ float  zzs[512];                 // 2 KB
    __shared__ float  wp[512];                  // 2 KB per-point window
    __shared__ unsigned long long best[512];    // 4 KB
    __shared__ unsigned short cand[512 * MAXC]; // 7 KB per-point candidate lists
    __shared__ unsigned int ccnt[512];          // 2 KB
    __shared__ unsigned int oq[OQCAP];          // 2 KB overflow queue
    __shared__ int ibuf[512];                   // 2 KB
    __shared__ unsigned int oqcnt, gflow;
    __shared__ double wsum[16];

    const int tid  = threadIdx.x;
    const int g    = blockIdx.x;                // 256 blocks: 8 per image
    const int lane = tid & 63, wv = tid >> 6;   // wv in [0,16)
    const size_t zoff = ((size_t)(g >> 3) << 18) + (size_t)((g & 7) << 9);
    const float* zb = z + zoff;

    // ---- init + stage eeL + stage bB (coalesced uint4, once per block)
    eeL[tid] = ee[tid];
    if (tid < 512) { best[tid] = 0xFFFFFFFFFFFFFFFFull; ccnt[tid] = 0; }
    if (tid == 0) { oqcnt = 0; gflow = 0; }
    {
        const uint4* src = (const uint4*)ehi;   // 8192 packets of 16 B
        uint4* dst = (uint4*)bB;
#pragma unroll
        for (int i = 0; i < 8; ++i)
            dst[i * 1024 + tid] = src[i * 1024 + tid];
    }

    // ---- zz: exact 64-chain fmaf order (same as r1-r10), loads batched 16-wide
    if (tid < 512) {
        float a = 0.f;
#pragma unroll
        for (int kb = 0; kb < 4; ++kb) {
            float t[16];
#pragma unroll
            for (int i = 0; i < 16; ++i)
                t[i] = zb[(size_t)(kb * 16 + i) * 4096 + tid];
#pragma unroll
            for (int i = 0; i < 16; ++i) a = fmaf(t[i], t[i], a);
        }
        zzs[tid] = a;
    }

    // ---- A-fragment (z-hi) + per-point rigorous window (r6-r10 formula), batched loads
    bf16x8 ah[4];
    {
        int h = lane >> 5;
        int pl = wv * 32 + (lane & 31);
        float s1 = 0.f, sd = 0.f;
#pragma unroll
        for (int kt = 0; kt < 4; ++kt) {
            float t[8];
#pragma unroll
            for (int i = 0; i < 8; ++i)
                t[i] = zb[(size_t)(kt * 16 + h * 8 + i) * 4096 + pl];
#pragma unroll
            for (int i = 0; i < 8; ++i) {
                float x = t[i];
                unsigned short hb = rne_bf16(x);
                float hf = __uint_as_float((unsigned)hb << 16);
                ah[kt][i] = (short)hb;
                s1 += fabsf(x);
                sd += fabsf(x - hf);
            }
        }
        s1 += __shfl_xor(s1, 32);
        sd += __shfl_xor(sd, 32);
        // W = 2*eps_data bound (x2 margin) + 4e-5 (d<->s offsets) + 1e-4 margin
        if (lane < 32) wp[pl] = 4.f * (s1 * 1.907e-6f + sd * 9.785e-4f) + 1.4e-4f;
    }
    __syncthreads();                            // bB/eeL/zzs/wp visible

    float m[16];
#pragma unroll
    for (int r = 0; r < 16; ++r) m[r] = 3.4e38f;

#define LOADL(B0, B1, B2, B3, EV, ntv) do {                         \
    int _o = (ntv) * 256 + lane;                                    \
    B0 = bB[_o]; B1 = bB[_o + 64]; B2 = bB[_o + 128]; B3 = bB[_o + 192]; \
    EV = eeL[(ntv) * 32 + (lane & 31)];                             \
} while (0)

#define SW1(B0, B1, B2, B3, EV) do {                                \
    f32x16 acc;                                                     \
    _Pragma("unroll")                                               \
    for (int _r = 0; _r < 16; ++_r) acc[_r] = 0.f;                  \
    acc = __builtin_amdgcn_mfma_f32_32x32x16_bf16(ah[0], B0, acc, 0, 0, 0); \
    acc = __builtin_amdgcn_mfma_f32_32x32x16_bf16(ah[1], B1, acc, 0, 0, 0); \
    acc = __builtin_amdgcn_mfma_f32_32x32x16_bf16(ah[2], B2, acc, 0, 0, 0); \
    acc = __builtin_amdgcn_mfma_f32_32x32x16_bf16(ah[3], B3, acc, 0, 0, 0); \
    _Pragma("unroll")                                               \
    for (int _r = 0; _r < 16; ++_r) m[_r] = fminf(m[_r], fmaf(-2.f, acc[_r], EV)); \
} while (0)

    // ---- sweep 1: per-row min of s~ (B from LDS, ping-pong prefetch, barrier-free)
    {
        bf16x8 p0, p1, p2, p3, q0, q1, q2, q3;
        float eP, eQ;
        LOADL(p0, p1, p2, p3, eP, 0);
#pragma unroll 1
        for (int nt = 0; nt < 32; nt += 2) {
            LOADL(q0, q1, q2, q3, eQ, nt + 1);
            SW1(p0, p1, p2, p3, eP);
            if (nt + 2 < 32) LOADL(p0, p1, p2, p3, eP, nt + 2);
            SW1(q0, q1, q2, q3, eQ);
        }
    }
    // butterfly min across 32 col-lanes, then fold per-point window -> threshold
#pragma unroll
    for (int r = 0; r < 16; ++r) {
        for (int d2 = 1; d2 <= 16; d2 <<= 1)
            m[r] = fminf(m[r], __shfl_xor(m[r], d2));
        m[r] += wp[wv * 32 + 4 * (lane >> 5) + (r & 3) + 8 * (r >> 2)];
    }

#define ENQ(PL, JJ) do {                                                  \
    unsigned _s = atomicAdd(&ccnt[PL], 1u);                               \
    if (_s < MAXC) cand[(PL) * MAXC + _s] = (unsigned short)(JJ);         \
    else { unsigned _o = atomicAdd(&oqcnt, 1u);                           \
           if (_o < OQCAP) oq[_o] = ((unsigned)(PL) << 16) | (JJ);        \
           else gflow = 1; }                                              \
} while (0)

#define SW2(B0, B1, B2, B3, EV, NTV) do {                           \
    f32x16 acc;                                                     \
    _Pragma("unroll")                                               \
    for (int _r = 0; _r < 16; ++_r) acc[_r] = 0.f;                  \
    acc = __builtin_amdgcn_mfma_f32_32x32x16_bf16(ah[0], B0, acc, 0, 0, 0); \
    acc = __builtin_amdgcn_mfma_f32_32x32x16_bf16(ah[1], B1, acc, 0, 0, 0); \
    acc = __builtin_amdgcn_mfma_f32_32x32x16_bf16(ah[2], B2, acc, 0, 0, 0); \
    acc = __builtin_amdgcn_mfma_f32_32x32x16_bf16(ah[3], B3, acc, 0, 0, 0); \
    unsigned jj = (unsigned)((NTV) * 32 + (lane & 31));             \
    _Pragma("unroll")                                               \
    for (int _r = 0; _r < 16; ++_r) {                               \
        bool hit = fmaf(-2.f, acc[_r], EV) <= m[_r];                \
        if (__any(hit)) {                                           \
            if (hit) {                                              \
                int pl = wv * 32 + 4 * (lane >> 5) + (_r & 3) + 8 * (_r >> 2); \
                ENQ(pl, jj);                                        \
            }                                                       \
        }                                                           \
    }                                                               \
} while (0)

    // ---- sweep 2: recompute (bit-identical MFMA sequence), enqueue window hits
    {
        bf16x8 p0, p1, p2, p3, q0, q1, q2, q3;
        float eP, eQ;
        LOADL(p0, p1, p2, p3, eP, 0);
#pragma unroll 1
        for (int nt = 0; nt < 32; nt += 2) {
            LOADL(q0, q1, q2, q3, eQ, nt + 1);
            SW2(p0, p1, p2, p3, eP, nt);
            if (nt + 2 < 32) LOADL(p0, p1, p2, p3, eP, nt + 2);
            SW2(q0, q1, q2, q3, eQ, nt + 1);
        }
    }
    __syncthreads();

    // ---- exact refine (z from global L2-hot, batched loads; ~1-3 candidates/point)
    if (gflow) {
        if (tid < 512) {                        // never-taken safety net
            unsigned long long bk = 0xFFFFFFFFFFFFFFFFull;
            for (int j = 0; j < NUM_E; ++j) {
                unsigned long long k2 = key_glob(zb, zzs[tid], eeL[j], cb, tid, j);
                if (k2 < bk) bk = k2;
            }
            best[tid] = bk;
        }
    } else {
        if (tid < 512) {
            int n = (int)ccnt[tid]; if (n > MAXC) n = MAXC;
            unsigned long long bk = 0xFFFFFFFFFFFFFFFFull;
            for (int e = 0; e < n; ++e) {
                int j = (int)cand[tid * MAXC + e];
                unsigned long long k2 = key_glob(zb, zzs[tid], eeL[j], cb, tid, j);
                if (k2 < bk) bk = k2;
            }
            atomicMin(&best[tid], bk);
        }
        int no = (int)oqcnt; if (no > OQCAP) no = OQCAP;
        for (int e = tid; e < no; e += 1024) {
            unsigned u = oq[e];
            int pl = (int)(u >> 16), j = (int)(u & 0xFFFFu);
            atomicMin(&best[pl], key_glob(zb, zzs[pl], eeL[j], cb, pl, j));
        }
    }
    __syncthreads();
    if (tid < 512) {
        int bi = (int)(best[tid] & 0xFFFFFFFFull);
        ibuf[tid] = bi;
        idx_f[(size_t)g * 512 + tid] = (float)bi;
        atomicAdd(&counts[bi], 1);
    }
    __syncthreads();

    // ---- fused tail: z_q_st = fl(z + fl(q - z)); z float4s preloaded (MLP), float4 stores
    {
        int w4 = tid & 127, c8 = (tid >> 7) * 8;          // 128 pt-quads x 64 ch
        const float4* zb4 = (const float4*)zb;
        float4* zq4 = (float4*)(zq + zoff);
        size_t b0 = (size_t)ibuf[w4 * 4 + 0] << 6;
        size_t b1 = (size_t)ibuf[w4 * 4 + 1] << 6;
        size_t b2 = (size_t)ibuf[w4 * 4 + 2] << 6;
        size_t b3 = (size_t)ibuf[w4 * 4 + 3] << 6;
        float4 zv[8];
#pragma unroll
        for (int i = 0; i < 8; ++i) zv[i] = zb4[(size_t)(c8 + i) * 1024 + w4];
        double ls = 0.0;
#pragma unroll
        for (int i = 0; i < 8; ++i) {
            int c = c8 + i;
            float q0 = cb[b0 + c], q1 = cb[b1 + c], q2 = cb[b2 + c], q3 = cb[b3 + c];
            float t0 = q0 - zv[i].x, t1 = q1 - zv[i].y, t2 = q2 - zv[i].z, t3 = q3 - zv[i].w;
            zq4[(size_t)c * 1024 + w4] =
                make_float4(zv[i].x + t0, zv[i].y + t1, zv[i].z + t2, zv[i].w + t3);
            ls += (double)t0 * t0 + (double)t1 * t1 + (double)t2 * t2 + (double)t3 * t3;
        }
#pragma unroll
        for (int off = 32; off > 0; off >>= 1) ls += __shfl_down(ls, off);
        if (lane == 0) wsum[wv] = ls;
    }
    __syncthreads();
    if (tid == 0) {
        double s = 0.0;
#pragma unroll
        for (int i = 0; i < 16; ++i) s += wsum[i];
        partials[g] = s;
    }
}

// ---------------------------------------------------------------- scalars
__global__ __launch_bounds__(256) void vq_final(
    const int* __restrict__ counts, const double* __restrict__ partials,
    float* __restrict__ scalars)
{
    __shared__ double sh[256];
    __shared__ double sl[256];
    int t = threadIdx.x;
    double s = 0.0;
    for (int j = t; j < NUM_E; j += 256) {
        float em   = (float)counts[j] * (1.0f / 131072.0f);
        float term = em * logf(em + 1e-10f);
        s += (double)term;
    }
    double l = 0.0;
#pragma unroll
    for (int j = 0; j < AGRID / 256; ++j) l += partials[j * 256 + t];
    sh[t] = s;
    sl[t] = l;
    __syncthreads();
    for (int off = 128; off > 0; off >>= 1) {
        if (t < off) { sh[t] += sh[t + off]; sl[t] += sl[t + off]; }
        __syncthreads();
    }
    if (t == 0) {
        float mm = (float)(sl[0] / 8388608.0);
        scalars[0] = mm + 0.5f * mm;         // mean1 + BETA*mean2
        scalars[1] = expf(-(float)sh[0]);    // perplexity
    }
}

// ---------------------------------------------------------------- launch
extern "C" void kernel_launch(void* const* d_in, const int* in_sizes, int n_in,
                              void* d_out, int out_size, void* d_ws, size_t ws_size,
                              hipStream_t stream)
{
    const float* z  = (const float*)d_in[0];
    const float* cb = (const float*)d_in[1];
    float* out     = (float*)d_out;
    float* zq      = out;                    // [32,64,64,64]
    float* scalars = out + ZQ_ELEM;          // loss, perplexity
    float* idx_f   = out + ZQ_ELEM + 2;      // [32,64,64] as float

    int*            counts   = (int*)d_ws;                             // 4 KB
    double*         partials = (double*)((char*)d_ws + 4096);          // 2 KB
    float*          ee       = (float*)((char*)d_ws + 12288);          // 4 KB
    unsigned short* ehi      = (unsigned short*)((char*)d_ws + 16384); // 128 KB

    hipMemsetAsync(d_ws, 0, 4096, stream);                    // zero counts
    vq_prep  <<<4,     256, 0, stream>>>(cb, ee, ehi);
    vq_argmin<<<AGRID, 1024, 0, stream>>>(z, cb, ehi, ee, idx_f, counts, zq, partials);
    vq_final <<<1,     256, 0, stream>>>(counts, partials, scalars);
}